// Round 15
// baseline (339.578 us; speedup 1.0000x reference)
//
#include <hip/hip_runtime.h>
#include <hip/hip_bf16.h>

#define N_NODES 50000
#define N_EDGES 1600000
#define IN_C 256
#define HID_C 256
#define OUT_C 10
#define SLOT_CAP 96      // max degree; Poisson(32) max over 50K nodes ~60; 96 = 11 sigma
#define NBUCKET 196      // ceil(50000/256) dst-buckets of 256 nodes
#define CAP2 56          // per-(part-block,bucket) record cap; Poisson(20.9)+7.6 sigma
#define M_TILES 391      // (N_NODES+127)/128
#define PART_BLOCKS 391  // ceil((N_EDGES/4)/1024)
#define GEMM_BLOCKS 1568 // 8*196
#define PREP_BLOCKS 533  // 512 (Wt) + 20 (Wt2f) + 1 (flag zero)

typedef short bf16x8 __attribute__((ext_vector_type(8)));
typedef float f32x4 __attribute__((ext_vector_type(4)));

static __device__ __forceinline__ float b2f(short v) {
    unsigned u = (unsigned)(unsigned short)v << 16;
    return __builtin_bit_cast(float, u);
}
static __device__ __forceinline__ short f2b(float f) {
    __hip_bfloat16 h = __float2bfloat16(f);
    return __builtin_bit_cast(short, h);
}
static __device__ __forceinline__ int4 pack8i(float4 a, float4 b) {
    bf16x8 o;
    o[0] = f2b(a.x); o[1] = f2b(a.y); o[2] = f2b(a.z); o[3] = f2b(a.w);
    o[4] = f2b(b.x); o[5] = f2b(b.y); o[6] = f2b(b.z); o[7] = f2b(b.w);
    return __builtin_bit_cast(int4, o);
}

// ---------- launch 1: prep Wt (512) + Wt2f (20) + zero part_done flag (1) ----------
__global__ void k_prep(const float* __restrict__ W1l, const float* __restrict__ W1r,
                       const float* __restrict__ W2l, const float* __restrict__ W2r,
                       __hip_bfloat16* __restrict__ Wt, float* __restrict__ Wt2f,
                       int* __restrict__ part_done) {
    int bid = blockIdx.x;
    if (bid < 512) {
        int idx = bid * 256 + threadIdx.x;  // 512*256
        int n = idx >> 8, k = idx & 255;
        float v = (n < HID_C) ? W1l[k * HID_C + n] : W1r[k * HID_C + (n - HID_C)];
        Wt[idx] = __float2bfloat16(v);
    } else if (bid < 532) {
        int idx = (bid - 512) * 256 + threadIdx.x;  // 20*256
        int r = idx >> 8, k = idx & 255;
        if (r < OUT_C) Wt2f[r * 256 + k] = W2l[k * OUT_C + r];
        else           Wt2f[(16 + r - OUT_C) * 256 + k] = W2r[k * OUT_C + (r - OUT_C)];
    } else {
        if (threadIdx.x == 0) *part_done = 0;
    }
}

// ---------- launch 2: part (0..390) + GEMM1 (391..1958) + bucket (1959..2154) --------
// part: per-block PRIVATE ebuf2 region [pb][bucket][CAP2] -> every ebuf2/cnt2 cache
//   line has exactly ONE writer. After the block's agent-RELEASE (wbl2), any reader's
//   copy is either the writer's own complete clean line (same-XCD hit) or a fresh L3
//   fetch (first touch) -> no stale-partial-line hazard. No global cursors needed.
// bucket: dispatched LAST (producers-first => deadlock-free), spins RELAXED on
//   part_done==391, then reads ebuf2/cnt2 with plain loads.
// gemm (R7-proven): 128x128 tile, BK=64, reg-staged prefetch, fused f32->bf16,
//   XCD-aware flat-id swizzle (offset 391 = 7 mod 8, bijective relabel), LDS C epilogue.
__global__ __launch_bounds__(256) void k_gpb(
        const int* __restrict__ src, const int* __restrict__ dst,
        int* __restrict__ part_done, int* __restrict__ ebuf2,
        unsigned char* __restrict__ cnt2,
        int* __restrict__ cnt, unsigned short* __restrict__ slots,
        const float* __restrict__ X, const __hip_bfloat16* __restrict__ Wt,
        const float* __restrict__ b1,
        __hip_bfloat16* __restrict__ Ab, __hip_bfloat16* __restrict__ Bh) {
    __shared__ short Smem[2 * 128 * 64];   // gemm: As|Bs then C-tile; part/bucket: counters
    int tid = threadIdx.x;

    if (blockIdx.x < PART_BLOCKS) {
        // ================= part path =================
        int* pos = (int*)Smem;             // [196] per-bucket cursors (block-private!)
        int pb = blockIdx.x;
        if (tid < NBUCKET) pos[tid] = 0;
        __syncthreads();

        int4 s[4], d[4];
        bool valid[4];
#pragma unroll
        for (int q = 0; q < 4; ++q) {
            int idx = pb * 1024 + q * 256 + tid;    // int4 index, 4 edges each
            valid[q] = (idx < N_EDGES / 4);
            if (valid[q]) {
                s[q] = ((const int4*)src)[idx];
                d[q] = ((const int4*)dst)[idx];
            }
        }
#pragma unroll
        for (int q = 0; q < 4; ++q) {
            if (valid[q]) {
                int ss[4] = { s[q].x, s[q].y, s[q].z, s[q].w };
                int dd[4] = { d[q].x, d[q].y, d[q].z, d[q].w };
#pragma unroll
                for (int e = 0; e < 4; ++e) {
                    int b = dd[e] >> 8;
                    int p = atomicAdd(&pos[b], 1);
                    if (p < CAP2)
                        ebuf2[((size_t)pb * NBUCKET + b) * CAP2 + p] =
                            ss[e] | ((dd[e] & 255) << 16);
                }
            }
        }
        __syncthreads();
        if (tid < NBUCKET) {
            int c = pos[tid];
            cnt2[(size_t)pb * NBUCKET + tid] = (unsigned char)(c > CAP2 ? CAP2 : c);
        }
        __syncthreads();
        if (tid == 0)   // RELEASE: wbl2 flushes this XCD's dirty lines to L3
            __hip_atomic_fetch_add(part_done, 1, __ATOMIC_RELEASE, __HIP_MEMORY_SCOPE_AGENT);
        return;
    }

    if (blockIdx.x >= PART_BLOCKS + GEMM_BLOCKS) {
        // ================= bucket path (consumers last) =================
        if (tid == 0) {
            while (__hip_atomic_load(part_done, __ATOMIC_RELAXED,
                                     __HIP_MEMORY_SCOPE_AGENT) < PART_BLOCKS)
                __builtin_amdgcn_s_sleep(8);
        }
        __syncthreads();
        asm volatile("" ::: "memory");

        int* lcnt = (int*)Smem;
        int b = blockIdx.x - PART_BLOCKS - GEMM_BLOCKS;
        lcnt[tid] = 0;
        __syncthreads();
        for (int blk = tid; blk < PART_BLOCKS; blk += 256) {
            int len = cnt2[(size_t)blk * NBUCKET + b];
            const int* base2 = ebuf2 + ((size_t)blk * NBUCKET + b) * CAP2;
            for (int i = 0; i < len; ++i) {
                int rec = base2[i];
                int dl = (rec >> 16) & 255;
                int p = atomicAdd(&lcnt[dl], 1);
                if (p < SLOT_CAP)
                    slots[(size_t)(b * 256 + dl) * SLOT_CAP + p] = (unsigned short)(rec & 0xFFFF);
            }
        }
        __syncthreads();
        int nid = b * 256 + tid;
        if (nid < N_NODES) cnt[nid] = lcnt[tid];
        return;
    }

    // ================= GEMM1 path =================
    short* As = Smem;
    short* Bs = Smem + 128 * 64;
    int fid = blockIdx.x - PART_BLOCKS;
    int xcd = fid & 7, slot = fid >> 3;
    int m_t = (slot >> 2) * 8 + xcd;
    if (m_t >= M_TILES) return;            // block-uniform guard
    int n_t = slot & 3;
    int m_base = m_t * 128;
    int n_base = n_t * 128;

    int wave = tid >> 6, lane = tid & 63;
    int r = lane & 15, quad = lane >> 4;
    int wr = wave >> 1, wc = wave & 1;

    // staging coords: thread covers 4 rows (q*32+srow) x 16B(bf16)/32B(f32) each
    int srow = tid >> 3;              // 0..31
    int kb8  = (tid & 7) * 16;        // byte offset in 128B bf16 row-slice
    int kelem = (tid & 7) * 8;        // element offset in 64-elem k-slice
    int swz  = kb8 ^ ((srow & 7) << 4);

    f32x4 acc[4][4];
#pragma unroll
    for (int i = 0; i < 4; ++i)
#pragma unroll
        for (int j = 0; j < 4; ++j) acc[i][j] = f32x4{0.f, 0.f, 0.f, 0.f};

    int4 av[4], bv[4];
    // prologue: load K-step 0 (A from f32 X, convert in regs; B already bf16)
#pragma unroll
    for (int q = 0; q < 4; ++q) {
        int grow = m_base + q * 32 + srow;
        if (grow > N_NODES - 1) grow = N_NODES - 1;
        const float* xp = X + (size_t)grow * IN_C + kelem;
        av[q] = pack8i(*(const float4*)xp, *(const float4*)(xp + 4));
        int brow = n_base + q * 32 + srow;
        bv[q] = *(const int4*)((const char*)Wt + ((size_t)brow * 512 + kb8));
    }

    for (int kk = 0; kk < 4; ++kk) {
        if (kk) __syncthreads();                 // prior reads done before overwrite
#pragma unroll
        for (int q = 0; q < 4; ++q) {
            *(int4*)((char*)As + (size_t)((q * 32 + srow) * 128 + swz)) = av[q];
            *(int4*)((char*)Bs + (size_t)((q * 32 + srow) * 128 + swz)) = bv[q];
        }
        __syncthreads();

        if (kk < 3) {                            // prefetch next K-step during compute
            int ke = (kk + 1) * 64 + kelem;
            int kbyte = (kk + 1) * 128 + kb8;
#pragma unroll
            for (int q = 0; q < 4; ++q) {
                int grow = m_base + q * 32 + srow;
                if (grow > N_NODES - 1) grow = N_NODES - 1;
                const float* xp = X + (size_t)grow * IN_C + ke;
                av[q] = pack8i(*(const float4*)xp, *(const float4*)(xp + 4));
                int brow = n_base + q * 32 + srow;
                bv[q] = *(const int4*)((const char*)Wt + ((size_t)brow * 512 + kbyte));
            }
        }

#pragma unroll
        for (int s = 0; s < 2; ++s) {
            int kfb = (s * 64 + quad * 16) ^ ((r & 7) << 4);
            bf16x8 a[4], b[4];
#pragma unroll
            for (int i = 0; i < 4; ++i)
                a[i] = *(const bf16x8*)((const char*)As + (size_t)((wr * 64 + i * 16 + r) * 128) + kfb);
#pragma unroll
            for (int j = 0; j < 4; ++j)
                b[j] = *(const bf16x8*)((const char*)Bs + (size_t)((wc * 64 + j * 16 + r) * 128) + kfb);
#pragma unroll
            for (int i = 0; i < 4; ++i)
#pragma unroll
                for (int j = 0; j < 4; ++j)
                    acc[i][j] = __builtin_amdgcn_mfma_f32_16x16x32_bf16(a[i], b[j], acc[i][j], 0, 0, 0);
        }
    }

    // ---- C epilogue via LDS: scatter acc (bf16) into 128x128 tile, then coalesced copy ----
    __syncthreads();                      // all waves done reading As/Bs
    short* Cs = Smem;                     // 128 rows x 128 cols bf16, 256B rows, swizzled
    bool left = (n_base < HID_C);         // block-uniform (n_t 0,1 -> Ab; 2,3 -> Bh)
#pragma unroll
    for (int j = 0; j < 4; ++j) {
        int coll = wc * 64 + 16 * j + r;  // local col 0..127
        float bias = left ? 0.f : b1[n_base + coll - HID_C];
#pragma unroll
        for (int i = 0; i < 4; ++i) {
#pragma unroll
            for (int ii = 0; ii < 4; ++ii) {
                int rowl = wr * 64 + 16 * i + quad * 4 + ii;
                int byteoff = (coll * 2) ^ ((rowl & 7) << 4);   // 16B-granular XOR swizzle
                *(short*)((char*)Cs + rowl * 256 + byteoff) = f2b(acc[i][j][ii] + bias);
            }
        }
    }
    __syncthreads();

    // copy-out: 16 lanes cover one 256B row (16B each) -> fully-coalesced lines
    int rrow = tid >> 4;                  // 0..15
    int cchunk = (tid & 15) * 16;         // byte offset in row
    size_t colbyte = left ? (size_t)(n_base * 2) : (size_t)((n_base - HID_C) * 2);
    char* outp = left ? (char*)Ab : (char*)Bh;
    for (int rb = 0; rb < 128; rb += 16) {
        int rowl = rb + rrow;
        int4 v = *(const int4*)((const char*)Cs + rowl * 256 + (cchunk ^ ((rowl & 7) << 4)));
        int grow = m_base + rowl;
        if (grow < N_NODES)
            *(int4*)(outp + (size_t)grow * 512 + colbyte + cchunk) = v;
    }
}

// ---------- fused: layer1 mean-agg + relu + GEMM2 epilogue -> CDl/CDr ----------
// CDl [node][12] f32 (48B rows, 2.4 MB -> XCD-L2-resident for agg2's random gather);
// CDr [node][12] f32, read once sequentially by agg2.
__global__ __launch_bounds__(256) void k_agg1f(
        const __hip_bfloat16* __restrict__ Ab, const __hip_bfloat16* __restrict__ Bh,
        const int* __restrict__ cnt, const unsigned short* __restrict__ slots,
        const float* __restrict__ Wt2f, const float* __restrict__ b2,
        float* __restrict__ CDl, float* __restrict__ CDr) {
    int wave = threadIdx.x >> 6, lane = threadIdx.x & 63;
    int nid = blockIdx.x * 4 + wave;          // grid 12500 -> exact
    int half = lane >> 5;
    int c8 = (lane & 31) * 8;
    const unsigned short* row = slots + (size_t)nid * SLOT_CAP;
    int n = cnt[nid];
    if (n > SLOT_CAP) n = SLOT_CAP;
    int mid = (n + 1) >> 1;
    int beg = half ? mid : 0;
    int end = half ? n : mid;

    float s0[8], s1[8], s2[8], s3[8];
#pragma unroll
    for (int j = 0; j < 8; ++j) { s0[j] = 0.f; s1[j] = 0.f; s2[j] = 0.f; s3[j] = 0.f; }

    const __hip_bfloat16* abc = Ab + c8;
    int e = beg;
    for (; e + 4 <= end; e += 4) {
        int i0 = row[e], i1 = row[e + 1], i2 = row[e + 2], i3 = row[e + 3];
        bf16x8 v0 = *(const bf16x8*)(abc + (size_t)i0 * HID_C);
        bf16x8 v1 = *(const bf16x8*)(abc + (size_t)i1 * HID_C);
        bf16x8 v2 = *(const bf16x8*)(abc + (size_t)i2 * HID_C);
        bf16x8 v3 = *(const bf16x8*)(abc + (size_t)i3 * HID_C);
#pragma unroll
        for (int j = 0; j < 8; ++j) {
            s0[j] += b2f(v0[j]); s1[j] += b2f(v1[j]);
            s2[j] += b2f(v2[j]); s3[j] += b2f(v3[j]);
        }
    }
    for (; e < end; ++e) {
        int i0 = row[e];
        bf16x8 v0 = *(const bf16x8*)(abc + (size_t)i0 * HID_C);
#pragma unroll
        for (int j = 0; j < 8; ++j) s0[j] += b2f(v0[j]);
    }
#pragma unroll
    for (int j = 0; j < 8; ++j) s0[j] += (s1[j] + s2[j]) + s3[j];
#pragma unroll
    for (int j = 0; j < 8; ++j) s0[j] += __shfl_down(s0[j], 32, 64);

    // h = relu(mean + Bh) computed on half0, broadcast to half1
    float h[8];
    float inv = 1.f / fmaxf((float)n, 1.f);
    if (half == 0) {
        bf16x8 bb = *(const bf16x8*)(Bh + (size_t)nid * HID_C + c8);
#pragma unroll
        for (int j = 0; j < 8; ++j)
            h[j] = fmaxf(s0[j] * inv + b2f(bb[j]), 0.f);
    }
#pragma unroll
    for (int j = 0; j < 8; ++j) h[j] = __shfl(h[j], lane & 31, 64);

    // 10 dot products with W2 (fp32), reduce over 32 lanes of this half
    const float* wbase = Wt2f + (half ? 16 * 256 : 0);
    float acc[10];
#pragma unroll
    for (int j = 0; j < 10; ++j) {
        f32x4 w0 = *(const f32x4*)(wbase + j * 256 + c8);
        f32x4 w1 = *(const f32x4*)(wbase + j * 256 + c8 + 4);
        float a = h[0] * w0[0] + h[1] * w0[1] + h[2] * w0[2] + h[3] * w0[3]
                + h[4] * w1[0] + h[5] * w1[1] + h[6] * w1[2] + h[7] * w1[3];
#pragma unroll
        for (int off = 16; off > 0; off >>= 1)
            a += __shfl_down(a, off, 32);
        acc[j] = a;
    }
    if ((lane & 31) == 0) {
        if (half == 0) {
            float* o = CDl + (size_t)nid * 12;
#pragma unroll
            for (int j = 0; j < 10; ++j) o[j] = acc[j];
            o[10] = 0.f; o[11] = 0.f;
        } else {
            float* o = CDr + (size_t)nid * 12;
#pragma unroll
            for (int j = 0; j < 10; ++j) o[j] = acc[j] + b2[j];
        }
    }
}

// ---------- layer2 aggregation + log_softmax: two nodes per wave (32 lanes each) ----------
__global__ __launch_bounds__(256) void k_agg2(
        const float* __restrict__ CDl, const float* __restrict__ CDr,
        const int* __restrict__ cnt, const unsigned short* __restrict__ slots,
        float* __restrict__ out) {
    int wave = threadIdx.x >> 6, lane = threadIdx.x & 63;
    int half = lane >> 5, sub = lane & 31;
    int nid = blockIdx.x * 8 + wave * 2 + half;   // grid 6250 -> exact
    const unsigned short* row = slots + (size_t)nid * SLOT_CAP;
    int n = cnt[nid];
    if (n > SLOT_CAP) n = SLOT_CAP;
    float s[10];
#pragma unroll
    for (int j = 0; j < 10; ++j) s[j] = 0.f;
    for (int e = sub; e < n; e += 32) {
        const float* cr = CDl + (size_t)row[e] * 12;   // 48B row, L2-resident slab
        f32x4 v0 = *(const f32x4*)cr;
        f32x4 v1 = *(const f32x4*)(cr + 4);
        f32x4 v2 = *(const f32x4*)(cr + 8);   // cols 8..11 (10,11 zeroed)
#pragma unroll
        for (int j = 0; j < 4; ++j) { s[j] += v0[j]; s[4 + j] += v1[j]; }
        s[8] += v2[0]; s[9] += v2[1];
    }
#pragma unroll
    for (int j = 0; j < 10; ++j)
#pragma unroll
        for (int off = 16; off > 0; off >>= 1)
            s[j] += __shfl_down(s[j], off, 32);
    if (sub == 0) {
        float inv = 1.f / fmaxf((float)n, 1.f);
        const float* rr = CDr + (size_t)nid * 12;
        float z[10], mx = -1e30f;
#pragma unroll
        for (int j = 0; j < 10; ++j) {
            z[j] = s[j] * inv + rr[j];
            mx = fmaxf(mx, z[j]);
        }
        float se = 0.f;
#pragma unroll
        for (int j = 0; j < 10; ++j) se += expf(z[j] - mx);
        float lse = logf(se) + mx;
#pragma unroll
        for (int j = 0; j < 10; ++j) out[(size_t)nid * OUT_C + j] = z[j] - lse;
    }
}

extern "C" void kernel_launch(void* const* d_in, const int* in_sizes, int n_in,
                              void* d_out, int out_size, void* d_ws, size_t ws_size,
                              hipStream_t stream) {
    const float* x   = (const float*)d_in[0];
    const int*   ei  = (const int*)d_in[1];
    const float* W1l = (const float*)d_in[2];
    const float* W1r = (const float*)d_in[3];
    const float* b1  = (const float*)d_in[4];
    const float* W2l = (const float*)d_in[5];
    const float* W2r = (const float*)d_in[6];
    const float* b2  = (const float*)d_in[7];
    float* out = (float*)d_out;
    const int* src = ei;
    const int* dst = ei + N_EDGES;

    char* w = (char*)d_ws;
    size_t off = 0;
    auto alloc = [&](size_t bytes) -> void* {
        void* p = w + off;
        off = (off + bytes + 255) & ~(size_t)255;
        return p;
    };
    __hip_bfloat16* Wt   = (__hip_bfloat16*)alloc((size_t)2 * HID_C * IN_C * 2);
    float*          Wt2f = (float*)alloc((size_t)32 * 256 * 4);
    __hip_bfloat16* Ab   = (__hip_bfloat16*)alloc((size_t)N_NODES * HID_C * 2);
    __hip_bfloat16* Bh   = (__hip_bfloat16*)alloc((size_t)N_NODES * HID_C * 2);
    float* CDl = (float*)alloc((size_t)N_NODES * 12 * 4);
    float* CDr = (float*)alloc((size_t)N_NODES * 12 * 4);
    int* cnt      = (int*)alloc((size_t)N_NODES * 4);
    unsigned short* slots = (unsigned short*)alloc((size_t)N_NODES * SLOT_CAP * 2);
    int* part_done = (int*)alloc(4);
    int* ebuf2     = (int*)alloc((size_t)PART_BLOCKS * NBUCKET * CAP2 * 4);
    unsigned char* cnt2 = (unsigned char*)alloc((size_t)PART_BLOCKS * NBUCKET);

    k_prep<<<PREP_BLOCKS, 256, 0, stream>>>(W1l, W1r, W2l, W2r, Wt, Wt2f, part_done);
    k_gpb<<<PART_BLOCKS + GEMM_BLOCKS + NBUCKET, 256, 0, stream>>>(
        src, dst, part_done, ebuf2, cnt2, cnt, slots, x, Wt, b1, Ab, Bh);
    k_agg1f<<<N_NODES / 4, 256, 0, stream>>>(Ab, Bh, cnt, slots, Wt2f, b2, CDl, CDr);
    k_agg2<<<N_NODES / 8, 256, 0, stream>>>(CDl, CDr, cnt, slots, out);
}

// Round 16
// 320.203 us; speedup vs baseline: 1.0605x; 1.0605x over previous
//
#include <hip/hip_runtime.h>
#include <hip/hip_bf16.h>

#define N_NODES 50000
#define N_EDGES 1600000
#define IN_C 256
#define HID_C 256
#define OUT_C 10
#define SLOT_CAP 96      // max degree; Poisson(32) max over 50K nodes ~60; 96 = 11 sigma
#define NBUCKET 196      // ceil(50000/256) dst-buckets of 256 nodes
#define CAP2 56          // per-(part-block,bucket) cap; Poisson(20.9), P(>56) ~ 8e-11
#define M_TILES 391      // (N_NODES+127)/128
#define PART_BLOCKS 391  // ceil((N_EDGES/4)/1024)
#define GEMM_BLOCKS 1568 // 8*196
#define PREP_BLOCKS 532  // 512 (Wt) + 20 (Wt2f)

typedef short bf16x8 __attribute__((ext_vector_type(8)));
typedef float f32x4 __attribute__((ext_vector_type(4)));

static __device__ __forceinline__ float b2f(short v) {
    unsigned u = (unsigned)(unsigned short)v << 16;
    return __builtin_bit_cast(float, u);
}
static __device__ __forceinline__ short f2b(float f) {
    __hip_bfloat16 h = __float2bfloat16(f);
    return __builtin_bit_cast(short, h);
}
static __device__ __forceinline__ int4 pack8i(float4 a, float4 b) {
    bf16x8 o;
    o[0] = f2b(a.x); o[1] = f2b(a.y); o[2] = f2b(a.z); o[3] = f2b(a.w);
    o[4] = f2b(b.x); o[5] = f2b(b.y); o[6] = f2b(b.z); o[7] = f2b(b.w);
    return __builtin_bit_cast(int4, o);
}

// ---------- launch 1: prep (0..531) + edge partition (532..922) ----------
// part writes block-PRIVATE ebuf2 segments [pb][bucket][CAP2] with LDS cursors only —
// no global cursors, no memset, no global atomics. Launch boundary before k_gb's
// bucket consumer provides full coherence (R15 lesson: intra-launch spin costs more
// than the launch gap it saves).
__global__ __launch_bounds__(256) void k_pp(
        const float* __restrict__ W1l, const float* __restrict__ W1r,
        const float* __restrict__ W2l, const float* __restrict__ W2r,
        __hip_bfloat16* __restrict__ Wt, float* __restrict__ Wt2f,
        const int* __restrict__ src, const int* __restrict__ dst,
        int* __restrict__ ebuf2, unsigned char* __restrict__ cnt2) {
    __shared__ int pos[NBUCKET];
    int tid = threadIdx.x;
    int bid = blockIdx.x;

    if (bid < 512) {
        int idx = bid * 256 + tid;          // 512*256
        int n = idx >> 8, k = idx & 255;
        float v = (n < HID_C) ? W1l[k * HID_C + n] : W1r[k * HID_C + (n - HID_C)];
        Wt[idx] = __float2bfloat16(v);
        return;
    }
    if (bid < PREP_BLOCKS) {
        int idx = (bid - 512) * 256 + tid;  // 20*256
        int r = idx >> 8, k = idx & 255;
        if (r < OUT_C) Wt2f[r * 256 + k] = W2l[k * OUT_C + r];
        else           Wt2f[(16 + r - OUT_C) * 256 + k] = W2r[k * OUT_C + (r - OUT_C)];
        return;
    }

    // ---- edge partition ----
    int pb = bid - PREP_BLOCKS;             // 0..390
    if (tid < NBUCKET) pos[tid] = 0;
    __syncthreads();

    int4 s[4], d[4];
    bool valid[4];
#pragma unroll
    for (int q = 0; q < 4; ++q) {
        int idx = pb * 1024 + q * 256 + tid;    // int4 index, 4 edges each
        valid[q] = (idx < N_EDGES / 4);
        if (valid[q]) {
            s[q] = ((const int4*)src)[idx];
            d[q] = ((const int4*)dst)[idx];
        }
    }
#pragma unroll
    for (int q = 0; q < 4; ++q) {
        if (valid[q]) {
            int ss[4] = { s[q].x, s[q].y, s[q].z, s[q].w };
            int dd[4] = { d[q].x, d[q].y, d[q].z, d[q].w };
#pragma unroll
            for (int e = 0; e < 4; ++e) {
                int b = dd[e] >> 8;
                int p = atomicAdd(&pos[b], 1);
                if (p < CAP2)
                    ebuf2[((size_t)pb * NBUCKET + b) * CAP2 + p] =
                        ss[e] | ((dd[e] & 255) << 16);
            }
        }
    }
    __syncthreads();
    if (tid < NBUCKET) {
        int c = pos[tid];
        cnt2[(size_t)pb * NBUCKET + tid] = (unsigned char)(c > CAP2 ? CAP2 : c);
    }
}

// ---------- launch 2: bucket (0..195) + GEMM1 (196..1763) ----------
// bucket reads the single-writer ebuf2/cnt2 (produced last launch); its ~20 us hides
// under gemm's runtime (R13-proven). GEMM1 (R7-proven): 128x128 tile, BK=64, 4 waves,
// reg-staged prefetch, fused f32->bf16, XCD-aware swizzle, LDS C epilogue.
__global__ __launch_bounds__(256) void k_gb(
        const int* __restrict__ ebuf2, const unsigned char* __restrict__ cnt2,
        int* __restrict__ cnt, unsigned short* __restrict__ slots,
        const float* __restrict__ X, const __hip_bfloat16* __restrict__ Wt,
        const float* __restrict__ b1,
        __hip_bfloat16* __restrict__ Ab, __hip_bfloat16* __restrict__ Bh) {
    __shared__ short Smem[2 * 128 * 64];   // gemm: As|Bs then C-tile; bucket: 1KB counters
    int tid = threadIdx.x;

    if (blockIdx.x < NBUCKET) {
        // ================= bucket path =================
        int* lcnt = (int*)Smem;
        int b = blockIdx.x;
        lcnt[tid] = 0;
        __syncthreads();
        for (int blk = tid; blk < PART_BLOCKS; blk += 256) {
            int len = cnt2[(size_t)blk * NBUCKET + b];
            const int* base2 = ebuf2 + ((size_t)blk * NBUCKET + b) * CAP2;
            for (int i = 0; i < len; ++i) {
                int rec = base2[i];
                int dl = (rec >> 16) & 255;
                int p = atomicAdd(&lcnt[dl], 1);
                if (p < SLOT_CAP)
                    slots[(size_t)(b * 256 + dl) * SLOT_CAP + p] = (unsigned short)(rec & 0xFFFF);
            }
        }
        __syncthreads();
        int nid = b * 256 + tid;
        if (nid < N_NODES) cnt[nid] = lcnt[tid];
        return;
    }

    // ================= GEMM1 path =================
    short* As = Smem;
    short* Bs = Smem + 128 * 64;
    int fid = blockIdx.x - NBUCKET;
    int xcd = fid & 7, slot = fid >> 3;
    int m_t = (slot >> 2) * 8 + xcd;
    if (m_t >= M_TILES) return;            // block-uniform guard
    int n_t = slot & 3;
    int m_base = m_t * 128;
    int n_base = n_t * 128;

    int wave = tid >> 6, lane = tid & 63;
    int r = lane & 15, quad = lane >> 4;
    int wr = wave >> 1, wc = wave & 1;

    // staging coords: thread covers 4 rows (q*32+srow) x 16B(bf16)/32B(f32) each
    int srow = tid >> 3;              // 0..31
    int kb8  = (tid & 7) * 16;        // byte offset in 128B bf16 row-slice
    int kelem = (tid & 7) * 8;        // element offset in 64-elem k-slice
    int swz  = kb8 ^ ((srow & 7) << 4);

    f32x4 acc[4][4];
#pragma unroll
    for (int i = 0; i < 4; ++i)
#pragma unroll
        for (int j = 0; j < 4; ++j) acc[i][j] = f32x4{0.f, 0.f, 0.f, 0.f};

    int4 av[4], bv[4];
    // prologue: load K-step 0 (A from f32 X, convert in regs; B already bf16)
#pragma unroll
    for (int q = 0; q < 4; ++q) {
        int grow = m_base + q * 32 + srow;
        if (grow > N_NODES - 1) grow = N_NODES - 1;
        const float* xp = X + (size_t)grow * IN_C + kelem;
        av[q] = pack8i(*(const float4*)xp, *(const float4*)(xp + 4));
        int brow = n_base + q * 32 + srow;
        bv[q] = *(const int4*)((const char*)Wt + ((size_t)brow * 512 + kb8));
    }

    for (int kk = 0; kk < 4; ++kk) {
        if (kk) __syncthreads();                 // prior reads done before overwrite
#pragma unroll
        for (int q = 0; q < 4; ++q) {
            *(int4*)((char*)As + (size_t)((q * 32 + srow) * 128 + swz)) = av[q];
            *(int4*)((char*)Bs + (size_t)((q * 32 + srow) * 128 + swz)) = bv[q];
        }
        __syncthreads();

        if (kk < 3) {                            // prefetch next K-step during compute
            int ke = (kk + 1) * 64 + kelem;
            int kbyte = (kk + 1) * 128 + kb8;
#pragma unroll
            for (int q = 0; q < 4; ++q) {
                int grow = m_base + q * 32 + srow;
                if (grow > N_NODES - 1) grow = N_NODES - 1;
                const float* xp = X + (size_t)grow * IN_C + ke;
                av[q] = pack8i(*(const float4*)xp, *(const float4*)(xp + 4));
                int brow = n_base + q * 32 + srow;
                bv[q] = *(const int4*)((const char*)Wt + ((size_t)brow * 512 + kbyte));
            }
        }

#pragma unroll
        for (int s = 0; s < 2; ++s) {
            int kfb = (s * 64 + quad * 16) ^ ((r & 7) << 4);
            bf16x8 a[4], b[4];
#pragma unroll
            for (int i = 0; i < 4; ++i)
                a[i] = *(const bf16x8*)((const char*)As + (size_t)((wr * 64 + i * 16 + r) * 128) + kfb);
#pragma unroll
            for (int j = 0; j < 4; ++j)
                b[j] = *(const bf16x8*)((const char*)Bs + (size_t)((wc * 64 + j * 16 + r) * 128) + kfb);
#pragma unroll
            for (int i = 0; i < 4; ++i)
#pragma unroll
                for (int j = 0; j < 4; ++j)
                    acc[i][j] = __builtin_amdgcn_mfma_f32_16x16x32_bf16(a[i], b[j], acc[i][j], 0, 0, 0);
        }
    }

    // ---- C epilogue via LDS: scatter acc (bf16) into 128x128 tile, then coalesced copy ----
    __syncthreads();                      // all waves done reading As/Bs
    short* Cs = Smem;                     // 128 rows x 128 cols bf16, 256B rows, swizzled
    bool left = (n_base < HID_C);         // block-uniform (n_t 0,1 -> Ab; 2,3 -> Bh)
#pragma unroll
    for (int j = 0; j < 4; ++j) {
        int coll = wc * 64 + 16 * j + r;  // local col 0..127
        float bias = left ? 0.f : b1[n_base + coll - HID_C];
#pragma unroll
        for (int i = 0; i < 4; ++i) {
#pragma unroll
            for (int ii = 0; ii < 4; ++ii) {
                int rowl = wr * 64 + 16 * i + quad * 4 + ii;
                int byteoff = (coll * 2) ^ ((rowl & 7) << 4);   // 16B-granular XOR swizzle
                *(short*)((char*)Cs + rowl * 256 + byteoff) = f2b(acc[i][j][ii] + bias);
            }
        }
    }
    __syncthreads();

    // copy-out: 16 lanes cover one 256B row (16B each) -> fully-coalesced lines
    int rrow = tid >> 4;                  // 0..15
    int cchunk = (tid & 15) * 16;         // byte offset in row
    size_t colbyte = left ? (size_t)(n_base * 2) : (size_t)((n_base - HID_C) * 2);
    char* outp = left ? (char*)Ab : (char*)Bh;
    for (int rb = 0; rb < 128; rb += 16) {
        int rowl = rb + rrow;
        int4 v = *(const int4*)((const char*)Cs + rowl * 256 + (cchunk ^ ((rowl & 7) << 4)));
        int grow = m_base + rowl;
        if (grow < N_NODES)
            *(int4*)(outp + (size_t)grow * 512 + colbyte + cchunk) = v;
    }
}

// ---------- fused: layer1 mean-agg + relu + GEMM2 epilogue -> CDl/CDr ----------
// CDl [node][12] f32 (48B rows, 2.4 MB -> XCD-L2-resident for agg2's random gather);
// CDr [node][12] f32, read once sequentially by agg2.
__global__ __launch_bounds__(256) void k_agg1f(
        const __hip_bfloat16* __restrict__ Ab, const __hip_bfloat16* __restrict__ Bh,
        const int* __restrict__ cnt, const unsigned short* __restrict__ slots,
        const float* __restrict__ Wt2f, const float* __restrict__ b2,
        float* __restrict__ CDl, float* __restrict__ CDr) {
    int wave = threadIdx.x >> 6, lane = threadIdx.x & 63;
    int nid = blockIdx.x * 4 + wave;          // grid 12500 -> exact
    int half = lane >> 5;
    int c8 = (lane & 31) * 8;
    const unsigned short* row = slots + (size_t)nid * SLOT_CAP;
    int n = cnt[nid];
    if (n > SLOT_CAP) n = SLOT_CAP;
    int mid = (n + 1) >> 1;
    int beg = half ? mid : 0;
    int end = half ? n : mid;

    float s0[8], s1[8], s2[8], s3[8];
#pragma unroll
    for (int j = 0; j < 8; ++j) { s0[j] = 0.f; s1[j] = 0.f; s2[j] = 0.f; s3[j] = 0.f; }

    const __hip_bfloat16* abc = Ab + c8;
    int e = beg;
    for (; e + 4 <= end; e += 4) {
        int i0 = row[e], i1 = row[e + 1], i2 = row[e + 2], i3 = row[e + 3];
        bf16x8 v0 = *(const bf16x8*)(abc + (size_t)i0 * HID_C);
        bf16x8 v1 = *(const bf16x8*)(abc + (size_t)i1 * HID_C);
        bf16x8 v2 = *(const bf16x8*)(abc + (size_t)i2 * HID_C);
        bf16x8 v3 = *(const bf16x8*)(abc + (size_t)i3 * HID_C);
#pragma unroll
        for (int j = 0; j < 8; ++j) {
            s0[j] += b2f(v0[j]); s1[j] += b2f(v1[j]);
            s2[j] += b2f(v2[j]); s3[j] += b2f(v3[j]);
        }
    }
    for (; e < end; ++e) {
        int i0 = row[e];
        bf16x8 v0 = *(const bf16x8*)(abc + (size_t)i0 * HID_C);
#pragma unroll
        for (int j = 0; j < 8; ++j) s0[j] += b2f(v0[j]);
    }
#pragma unroll
    for (int j = 0; j < 8; ++j) s0[j] += (s1[j] + s2[j]) + s3[j];
#pragma unroll
    for (int j = 0; j < 8; ++j) s0[j] += __shfl_down(s0[j], 32, 64);

    // h = relu(mean + Bh) computed on half0, broadcast to half1
    float h[8];
    float inv = 1.f / fmaxf((float)n, 1.f);
    if (half == 0) {
        bf16x8 bb = *(const bf16x8*)(Bh + (size_t)nid * HID_C + c8);
#pragma unroll
        for (int j = 0; j < 8; ++j)
            h[j] = fmaxf(s0[j] * inv + b2f(bb[j]), 0.f);
    }
#pragma unroll
    for (int j = 0; j < 8; ++j) h[j] = __shfl(h[j], lane & 31, 64);

    // 10 dot products with W2 (fp32), reduce over 32 lanes of this half
    const float* wbase = Wt2f + (half ? 16 * 256 : 0);
    float acc[10];
#pragma unroll
    for (int j = 0; j < 10; ++j) {
        f32x4 w0 = *(const f32x4*)(wbase + j * 256 + c8);
        f32x4 w1 = *(const f32x4*)(wbase + j * 256 + c8 + 4);
        float a = h[0] * w0[0] + h[1] * w0[1] + h[2] * w0[2] + h[3] * w0[3]
                + h[4] * w1[0] + h[5] * w1[1] + h[6] * w1[2] + h[7] * w1[3];
#pragma unroll
        for (int off = 16; off > 0; off >>= 1)
            a += __shfl_down(a, off, 32);
        acc[j] = a;
    }
    if ((lane & 31) == 0) {
        if (half == 0) {
            float* o = CDl + (size_t)nid * 12;
#pragma unroll
            for (int j = 0; j < 10; ++j) o[j] = acc[j];
            o[10] = 0.f; o[11] = 0.f;
        } else {
            float* o = CDr + (size_t)nid * 12;
#pragma unroll
            for (int j = 0; j < 10; ++j) o[j] = acc[j] + b2[j];
        }
    }
}

// ---------- layer2 aggregation + log_softmax: two nodes per wave (32 lanes each) ----------
__global__ __launch_bounds__(256) void k_agg2(
        const float* __restrict__ CDl, const float* __restrict__ CDr,
        const int* __restrict__ cnt, const unsigned short* __restrict__ slots,
        float* __restrict__ out) {
    int wave = threadIdx.x >> 6, lane = threadIdx.x & 63;
    int half = lane >> 5, sub = lane & 31;
    int nid = blockIdx.x * 8 + wave * 2 + half;   // grid 6250 -> exact
    const unsigned short* row = slots + (size_t)nid * SLOT_CAP;
    int n = cnt[nid];
    if (n > SLOT_CAP) n = SLOT_CAP;
    float s[10];
#pragma unroll
    for (int j = 0; j < 10; ++j) s[j] = 0.f;
    for (int e = sub; e < n; e += 32) {
        const float* cr = CDl + (size_t)row[e] * 12;   // 48B row, L2-resident slab
        f32x4 v0 = *(const f32x4*)cr;
        f32x4 v1 = *(const f32x4*)(cr + 4);
        f32x4 v2 = *(const f32x4*)(cr + 8);   // cols 8..11 (10,11 zeroed)
#pragma unroll
        for (int j = 0; j < 4; ++j) { s[j] += v0[j]; s[4 + j] += v1[j]; }
        s[8] += v2[0]; s[9] += v2[1];
    }
#pragma unroll
    for (int j = 0; j < 10; ++j)
#pragma unroll
        for (int off = 16; off > 0; off >>= 1)
            s[j] += __shfl_down(s[j], off, 32);
    if (sub == 0) {
        float inv = 1.f / fmaxf((float)n, 1.f);
        const float* rr = CDr + (size_t)nid * 12;
        float z[10], mx = -1e30f;
#pragma unroll
        for (int j = 0; j < 10; ++j) {
            z[j] = s[j] * inv + rr[j];
            mx = fmaxf(mx, z[j]);
        }
        float se = 0.f;
#pragma unroll
        for (int j = 0; j < 10; ++j) se += expf(z[j] - mx);
        float lse = logf(se) + mx;
#pragma unroll
        for (int j = 0; j < 10; ++j) out[(size_t)nid * OUT_C + j] = z[j] - lse;
    }
}

extern "C" void kernel_launch(void* const* d_in, const int* in_sizes, int n_in,
                              void* d_out, int out_size, void* d_ws, size_t ws_size,
                              hipStream_t stream) {
    const float* x   = (const float*)d_in[0];
    const int*   ei  = (const int*)d_in[1];
    const float* W1l = (const float*)d_in[2];
    const float* W1r = (const float*)d_in[3];
    const float* b1  = (const float*)d_in[4];
    const float* W2l = (const float*)d_in[5];
    const float* W2r = (const float*)d_in[6];
    const float* b2  = (const float*)d_in[7];
    float* out = (float*)d_out;
    const int* src = ei;
    const int* dst = ei + N_EDGES;

    char* w = (char*)d_ws;
    size_t off = 0;
    auto alloc = [&](size_t bytes) -> void* {
        void* p = w + off;
        off = (off + bytes + 255) & ~(size_t)255;
        return p;
    };
    __hip_bfloat16* Wt   = (__hip_bfloat16*)alloc((size_t)2 * HID_C * IN_C * 2);
    float*          Wt2f = (float*)alloc((size_t)32 * 256 * 4);
    __hip_bfloat16* Ab   = (__hip_bfloat16*)alloc((size_t)N_NODES * HID_C * 2);
    __hip_bfloat16* Bh   = (__hip_bfloat16*)alloc((size_t)N_NODES * HID_C * 2);
    float* CDl = (float*)alloc((size_t)N_NODES * 12 * 4);
    float* CDr = (float*)alloc((size_t)N_NODES * 12 * 4);
    int* cnt      = (int*)alloc((size_t)N_NODES * 4);
    unsigned short* slots = (unsigned short*)alloc((size_t)N_NODES * SLOT_CAP * 2);
    int* ebuf2     = (int*)alloc((size_t)PART_BLOCKS * NBUCKET * CAP2 * 4);
    unsigned char* cnt2 = (unsigned char*)alloc((size_t)PART_BLOCKS * NBUCKET);

    k_pp<<<PREP_BLOCKS + PART_BLOCKS, 256, 0, stream>>>(W1l, W1r, W2l, W2r, Wt, Wt2f,
                                                        src, dst, ebuf2, cnt2);
    k_gb<<<NBUCKET + GEMM_BLOCKS, 256, 0, stream>>>(ebuf2, cnt2, cnt, slots,
                                                    x, Wt, b1, Ab, Bh);
    k_agg1f<<<N_NODES / 4, 256, 0, stream>>>(Ab, Bh, cnt, slots, Wt2f, b2, CDl, CDr);
    k_agg2<<<N_NODES / 8, 256, 0, stream>>>(CDl, CDr, cnt, slots, out);
}

// Round 17
// 313.311 us; speedup vs baseline: 1.0838x; 1.0220x over previous
//
#include <hip/hip_runtime.h>
#include <hip/hip_bf16.h>

#define N_NODES 50000
#define N_EDGES 1600000
#define IN_C 256
#define HID_C 256
#define OUT_C 10
#define SLOT_CAP 96      // max degree; Poisson(32) max over 50K nodes ~60; 96 = 11 sigma
#define NBUCKET 196      // ceil(50000/256) dst-buckets of 256 nodes
#define EBUF_CAP 9216    // per-bucket edge capacity; mean 8163, sigma 90 -> +11.7 sigma
#define M_TILES 391      // (N_NODES+127)/128
#define PART_BLOCKS 391  // ceil((N_EDGES/4)/1024)
#define PREP_BLOCKS 532  // 512 (Wt) + 20 (Wt2f)

typedef short bf16x8 __attribute__((ext_vector_type(8)));
typedef float f32x4 __attribute__((ext_vector_type(4)));

static __device__ __forceinline__ float b2f(short v) {
    unsigned u = (unsigned)(unsigned short)v << 16;
    return __builtin_bit_cast(float, u);
}
static __device__ __forceinline__ short f2b(float f) {
    __hip_bfloat16 h = __float2bfloat16(f);
    return __builtin_bit_cast(short, h);
}
static __device__ __forceinline__ int4 pack8i(float4 a, float4 b) {
    bf16x8 o;
    o[0] = f2b(a.x); o[1] = f2b(a.y); o[2] = f2b(a.z); o[3] = f2b(a.w);
    o[4] = f2b(b.x); o[5] = f2b(b.y); o[6] = f2b(b.z); o[7] = f2b(b.w);
    return __builtin_bit_cast(int4, o);
}

// ---------- launch 1: prep (blocks 0..531) + edge partition (blocks 532..922) ----------
// Independent chains: prep writes Wt/Wt2f from weights; part buckets the edge list.
__global__ __launch_bounds__(256) void k_pp(
        const float* __restrict__ W1l, const float* __restrict__ W1r,
        const float* __restrict__ W2l, const float* __restrict__ W2r,
        __hip_bfloat16* __restrict__ Wt, float* __restrict__ Wt2f,
        const int* __restrict__ src, const int* __restrict__ dst,
        int* __restrict__ g_cursor, int* __restrict__ ebuf) {
    __shared__ int pbuf[3 * 256];
    int tid = threadIdx.x;
    int bid = blockIdx.x;

    if (bid < 512) {
        int idx = bid * 256 + tid;          // 512*256
        int n = idx >> 8, k = idx & 255;
        float v = (n < HID_C) ? W1l[k * HID_C + n] : W1r[k * HID_C + (n - HID_C)];
        Wt[idx] = __float2bfloat16(v);
        return;
    }
    if (bid < PREP_BLOCKS) {
        int idx = (bid - 512) * 256 + tid;  // 20*256
        int r = idx >> 8, k = idx & 255;
        if (r < OUT_C) Wt2f[r * 256 + k] = W2l[k * OUT_C + r];
        else           Wt2f[(16 + r - OUT_C) * 256 + k] = W2r[k * OUT_C + (r - OUT_C)];
        return;
    }

    // ---- edge partition ----
    int* hist = pbuf;
    int* base = pbuf + 256;
    int* pos  = pbuf + 512;
    int pb = bid - PREP_BLOCKS;             // 0..390
    if (tid < NBUCKET) { hist[tid] = 0; pos[tid] = 0; }
    __syncthreads();

    int4 s[4], d[4];
    bool valid[4];
#pragma unroll
    for (int q = 0; q < 4; ++q) {
        int idx = pb * 1024 + q * 256 + tid;    // int4 index, 4 edges each
        valid[q] = (idx < N_EDGES / 4);
        if (valid[q]) {
            s[q] = ((const int4*)src)[idx];
            d[q] = ((const int4*)dst)[idx];
        }
    }
#pragma unroll
    for (int q = 0; q < 4; ++q) {
        if (valid[q]) {
            atomicAdd(&hist[d[q].x >> 8], 1);
            atomicAdd(&hist[d[q].y >> 8], 1);
            atomicAdd(&hist[d[q].z >> 8], 1);
            atomicAdd(&hist[d[q].w >> 8], 1);
        }
    }
    __syncthreads();
    if (tid < NBUCKET && hist[tid] > 0)
        base[tid] = atomicAdd(&g_cursor[tid], hist[tid]);
    __syncthreads();
#pragma unroll
    for (int q = 0; q < 4; ++q) {
        if (valid[q]) {
            int ss[4] = { s[q].x, s[q].y, s[q].z, s[q].w };
            int dd[4] = { d[q].x, d[q].y, d[q].z, d[q].w };
#pragma unroll
            for (int e = 0; e < 4; ++e) {
                int b = dd[e] >> 8;
                int p = base[b] + atomicAdd(&pos[b], 1);
                if (p < EBUF_CAP)
                    ebuf[b * EBUF_CAP + p] = ss[e] | ((dd[e] & 255) << 16);
            }
        }
    }
}

// ---------- launch 2: bucket (blocks 0..195) + GEMM1 (blocks 196..1763) ----------
// bucket depends only on part (launch 1); gemm depends only on prep (launch 1).
// bucket's ~20 us hides under gemm's runtime (same mechanism as the R11 part-fusion).
// GEMM1 (R7-proven): 128x128 tile, BK=64, 4 waves (2x2 of 64x64), reg-staged prefetch,
// f32->bf16 fused into A-staging, XCD-aware flat-id swizzle, LDS C epilogue.
// (offset 196 = 4 mod 8 relabels XCDs bijectively -> panel->XCD grouping preserved)
__global__ __launch_bounds__(256) void k_gb(
        const int* __restrict__ ebuf, const int* __restrict__ g_cursor,
        int* __restrict__ cnt, unsigned short* __restrict__ slots,
        const float* __restrict__ X, const __hip_bfloat16* __restrict__ Wt,
        const float* __restrict__ b1,
        __hip_bfloat16* __restrict__ Ab, __hip_bfloat16* __restrict__ Bh) {
    __shared__ short Smem[2 * 128 * 64];   // gemm: As|Bs then C-tile; bucket: 1KB counters
    int tid = threadIdx.x;

    if (blockIdx.x < NBUCKET) {
        // ================= bucket path =================
        int* lcnt = (int*)Smem;
        int b = blockIdx.x;
        lcnt[tid] = 0;
        __syncthreads();
        int n_e = g_cursor[b];
        if (n_e > EBUF_CAP) n_e = EBUF_CAP;
        const int* eb = ebuf + b * EBUF_CAP;
        int n4 = n_e >> 2;
        for (int t = tid; t < n4; t += 256) {
            int4 v = ((const int4*)eb)[t];
            int vv[4] = { v.x, v.y, v.z, v.w };
#pragma unroll
            for (int e = 0; e < 4; ++e) {
                int dl = (vv[e] >> 16) & 255;
                int sv = vv[e] & 0xFFFF;
                int p = atomicAdd(&lcnt[dl], 1);
                if (p < SLOT_CAP) slots[(size_t)(b * 256 + dl) * SLOT_CAP + p] = (unsigned short)sv;
            }
        }
        for (int t = (n4 << 2) + tid; t < n_e; t += 256) {
            int vv = eb[t];
            int dl = (vv >> 16) & 255;
            int sv = vv & 0xFFFF;
            int p = atomicAdd(&lcnt[dl], 1);
            if (p < SLOT_CAP) slots[(size_t)(b * 256 + dl) * SLOT_CAP + p] = (unsigned short)sv;
        }
        __syncthreads();
        int nid = b * 256 + tid;
        if (nid < N_NODES) cnt[nid] = lcnt[tid];
        return;
    }

    // ================= GEMM1 path =================
    short* As = Smem;
    short* Bs = Smem + 128 * 64;
    int fid = blockIdx.x - NBUCKET;
    int xcd = fid & 7, slot = fid >> 3;
    int m_t = (slot >> 2) * 8 + xcd;
    if (m_t >= M_TILES) return;            // block-uniform guard
    int n_t = slot & 3;
    int m_base = m_t * 128;
    int n_base = n_t * 128;

    int wave = tid >> 6, lane = tid & 63;
    int r = lane & 15, quad = lane >> 4;
    int wr = wave >> 1, wc = wave & 1;

    // staging coords: thread covers 4 rows (q*32+srow) x 16B(bf16)/32B(f32) each
    int srow = tid >> 3;              // 0..31
    int kb8  = (tid & 7) * 16;        // byte offset in 128B bf16 row-slice
    int kelem = (tid & 7) * 8;        // element offset in 64-elem k-slice
    int swz  = kb8 ^ ((srow & 7) << 4);

    f32x4 acc[4][4];
#pragma unroll
    for (int i = 0; i < 4; ++i)
#pragma unroll
        for (int j = 0; j < 4; ++j) acc[i][j] = f32x4{0.f, 0.f, 0.f, 0.f};

    int4 av[4], bv[4];
    // prologue: load K-step 0 (A from f32 X, convert in regs; B already bf16)
#pragma unroll
    for (int q = 0; q < 4; ++q) {
        int grow = m_base + q * 32 + srow;
        if (grow > N_NODES - 1) grow = N_NODES - 1;
        const float* xp = X + (size_t)grow * IN_C + kelem;
        av[q] = pack8i(*(const float4*)xp, *(const float4*)(xp + 4));
        int brow = n_base + q * 32 + srow;
        bv[q] = *(const int4*)((const char*)Wt + ((size_t)brow * 512 + kb8));
    }

    for (int kk = 0; kk < 4; ++kk) {
        if (kk) __syncthreads();                 // prior reads done before overwrite
#pragma unroll
        for (int q = 0; q < 4; ++q) {
            *(int4*)((char*)As + (size_t)((q * 32 + srow) * 128 + swz)) = av[q];
            *(int4*)((char*)Bs + (size_t)((q * 32 + srow) * 128 + swz)) = bv[q];
        }
        __syncthreads();

        if (kk < 3) {                            // prefetch next K-step during compute
            int ke = (kk + 1) * 64 + kelem;
            int kbyte = (kk + 1) * 128 + kb8;
#pragma unroll
            for (int q = 0; q < 4; ++q) {
                int grow = m_base + q * 32 + srow;
                if (grow > N_NODES - 1) grow = N_NODES - 1;
                const float* xp = X + (size_t)grow * IN_C + ke;
                av[q] = pack8i(*(const float4*)xp, *(const float4*)(xp + 4));
                int brow = n_base + q * 32 + srow;
                bv[q] = *(const int4*)((const char*)Wt + ((size_t)brow * 512 + kbyte));
            }
        }

#pragma unroll
        for (int s = 0; s < 2; ++s) {
            int kfb = (s * 64 + quad * 16) ^ ((r & 7) << 4);
            bf16x8 a[4], b[4];
#pragma unroll
            for (int i = 0; i < 4; ++i)
                a[i] = *(const bf16x8*)((const char*)As + (size_t)((wr * 64 + i * 16 + r) * 128) + kfb);
#pragma unroll
            for (int j = 0; j < 4; ++j)
                b[j] = *(const bf16x8*)((const char*)Bs + (size_t)((wc * 64 + j * 16 + r) * 128) + kfb);
#pragma unroll
            for (int i = 0; i < 4; ++i)
#pragma unroll
                for (int j = 0; j < 4; ++j)
                    acc[i][j] = __builtin_amdgcn_mfma_f32_16x16x32_bf16(a[i], b[j], acc[i][j], 0, 0, 0);
        }
    }

    // ---- C epilogue via LDS: scatter acc (bf16) into 128x128 tile, then coalesced copy ----
    __syncthreads();                      // all waves done reading As/Bs
    short* Cs = Smem;                     // 128 rows x 128 cols bf16, 256B rows, swizzled
    bool left = (n_base < HID_C);         // block-uniform (n_t 0,1 -> Ab; 2,3 -> Bh)
#pragma unroll
    for (int j = 0; j < 4; ++j) {
        int coll = wc * 64 + 16 * j + r;  // local col 0..127
        float bias = left ? 0.f : b1[n_base + coll - HID_C];
#pragma unroll
        for (int i = 0; i < 4; ++i) {
#pragma unroll
            for (int ii = 0; ii < 4; ++ii) {
                int rowl = wr * 64 + 16 * i + quad * 4 + ii;
                int byteoff = (coll * 2) ^ ((rowl & 7) << 4);   // 16B-granular XOR swizzle
                *(short*)((char*)Cs + rowl * 256 + byteoff) = f2b(acc[i][j][ii] + bias);
            }
        }
    }
    __syncthreads();

    // copy-out: 16 lanes cover one 256B row (16B each) -> fully-coalesced lines
    int rrow = tid >> 4;                  // 0..15
    int cchunk = (tid & 15) * 16;         // byte offset in row
    size_t colbyte = left ? (size_t)(n_base * 2) : (size_t)((n_base - HID_C) * 2);
    char* outp = left ? (char*)Ab : (char*)Bh;
    for (int rb = 0; rb < 128; rb += 16) {
        int rowl = rb + rrow;
        int4 v = *(const int4*)((const char*)Cs + rowl * 256 + (cchunk ^ ((rowl & 7) << 4)));
        int grow = m_base + rowl;
        if (grow < N_NODES)
            *(int4*)(outp + (size_t)grow * 512 + colbyte + cchunk) = v;
    }
}

// ---------- fused: layer1 mean-agg + relu + GEMM2 epilogue -> CDl/CDr ----------
// CDl [node][12] f32 (48B rows, 2.4 MB -> XCD-L2-resident for agg2's random gather);
// CDr [node][12] f32, read once sequentially by agg2.
__global__ __launch_bounds__(256) void k_agg1f(
        const __hip_bfloat16* __restrict__ Ab, const __hip_bfloat16* __restrict__ Bh,
        const int* __restrict__ cnt, const unsigned short* __restrict__ slots,
        const float* __restrict__ Wt2f, const float* __restrict__ b2,
        float* __restrict__ CDl, float* __restrict__ CDr) {
    int wave = threadIdx.x >> 6, lane = threadIdx.x & 63;
    int nid = blockIdx.x * 4 + wave;          // grid 12500 -> exact
    int half = lane >> 5;
    int c8 = (lane & 31) * 8;
    const unsigned short* row = slots + (size_t)nid * SLOT_CAP;
    int n = cnt[nid];
    if (n > SLOT_CAP) n = SLOT_CAP;
    int mid = (n + 1) >> 1;
    int beg = half ? mid : 0;
    int end = half ? n : mid;

    float s0[8], s1[8], s2[8], s3[8];
#pragma unroll
    for (int j = 0; j < 8; ++j) { s0[j] = 0.f; s1[j] = 0.f; s2[j] = 0.f; s3[j] = 0.f; }

    const __hip_bfloat16* abc = Ab + c8;
    int e = beg;
    for (; e + 4 <= end; e += 4) {
        int i0 = row[e], i1 = row[e + 1], i2 = row[e + 2], i3 = row[e + 3];
        bf16x8 v0 = *(const bf16x8*)(abc + (size_t)i0 * HID_C);
        bf16x8 v1 = *(const bf16x8*)(abc + (size_t)i1 * HID_C);
        bf16x8 v2 = *(const bf16x8*)(abc + (size_t)i2 * HID_C);
        bf16x8 v3 = *(const bf16x8*)(abc + (size_t)i3 * HID_C);
#pragma unroll
        for (int j = 0; j < 8; ++j) {
            s0[j] += b2f(v0[j]); s1[j] += b2f(v1[j]);
            s2[j] += b2f(v2[j]); s3[j] += b2f(v3[j]);
        }
    }
    for (; e < end; ++e) {
        int i0 = row[e];
        bf16x8 v0 = *(const bf16x8*)(abc + (size_t)i0 * HID_C);
#pragma unroll
        for (int j = 0; j < 8; ++j) s0[j] += b2f(v0[j]);
    }
#pragma unroll
    for (int j = 0; j < 8; ++j) s0[j] += (s1[j] + s2[j]) + s3[j];
#pragma unroll
    for (int j = 0; j < 8; ++j) s0[j] += __shfl_down(s0[j], 32, 64);

    // h = relu(mean + Bh) computed on half0, broadcast to half1
    float h[8];
    float inv = 1.f / fmaxf((float)n, 1.f);
    if (half == 0) {
        bf16x8 bb = *(const bf16x8*)(Bh + (size_t)nid * HID_C + c8);
#pragma unroll
        for (int j = 0; j < 8; ++j)
            h[j] = fmaxf(s0[j] * inv + b2f(bb[j]), 0.f);
    }
#pragma unroll
    for (int j = 0; j < 8; ++j) h[j] = __shfl(h[j], lane & 31, 64);

    // 10 dot products with W2 (fp32), reduce over 32 lanes of this half
    const float* wbase = Wt2f + (half ? 16 * 256 : 0);
    float acc[10];
#pragma unroll
    for (int j = 0; j < 10; ++j) {
        f32x4 w0 = *(const f32x4*)(wbase + j * 256 + c8);
        f32x4 w1 = *(const f32x4*)(wbase + j * 256 + c8 + 4);
        float a = h[0] * w0[0] + h[1] * w0[1] + h[2] * w0[2] + h[3] * w0[3]
                + h[4] * w1[0] + h[5] * w1[1] + h[6] * w1[2] + h[7] * w1[3];
#pragma unroll
        for (int off = 16; off > 0; off >>= 1)
            a += __shfl_down(a, off, 32);
        acc[j] = a;
    }
    if ((lane & 31) == 0) {
        if (half == 0) {
            float* o = CDl + (size_t)nid * 12;
#pragma unroll
            for (int j = 0; j < 10; ++j) o[j] = acc[j];
            o[10] = 0.f; o[11] = 0.f;
        } else {
            float* o = CDr + (size_t)nid * 12;
#pragma unroll
            for (int j = 0; j < 10; ++j) o[j] = acc[j] + b2[j];
        }
    }
}

// ---------- layer2 aggregation + log_softmax: two nodes per wave (32 lanes each) ----------
__global__ __launch_bounds__(256) void k_agg2(
        const float* __restrict__ CDl, const float* __restrict__ CDr,
        const int* __restrict__ cnt, const unsigned short* __restrict__ slots,
        float* __restrict__ out) {
    int wave = threadIdx.x >> 6, lane = threadIdx.x & 63;
    int half = lane >> 5, sub = lane & 31;
    int nid = blockIdx.x * 8 + wave * 2 + half;   // grid 6250 -> exact
    const unsigned short* row = slots + (size_t)nid * SLOT_CAP;
    int n = cnt[nid];
    if (n > SLOT_CAP) n = SLOT_CAP;
    float s[10];
#pragma unroll
    for (int j = 0; j < 10; ++j) s[j] = 0.f;
    for (int e = sub; e < n; e += 32) {
        const float* cr = CDl + (size_t)row[e] * 12;   // 48B row, L2-resident slab
        f32x4 v0 = *(const f32x4*)cr;
        f32x4 v1 = *(const f32x4*)(cr + 4);
        f32x4 v2 = *(const f32x4*)(cr + 8);   // cols 8..11 (10,11 zeroed)
#pragma unroll
        for (int j = 0; j < 4; ++j) { s[j] += v0[j]; s[4 + j] += v1[j]; }
        s[8] += v2[0]; s[9] += v2[1];
    }
#pragma unroll
    for (int j = 0; j < 10; ++j)
#pragma unroll
        for (int off = 16; off > 0; off >>= 1)
            s[j] += __shfl_down(s[j], off, 32);
    if (sub == 0) {
        float inv = 1.f / fmaxf((float)n, 1.f);
        const float* rr = CDr + (size_t)nid * 12;
        float z[10], mx = -1e30f;
#pragma unroll
        for (int j = 0; j < 10; ++j) {
            z[j] = s[j] * inv + rr[j];
            mx = fmaxf(mx, z[j]);
        }
        float se = 0.f;
#pragma unroll
        for (int j = 0; j < 10; ++j) se += expf(z[j] - mx);
        float lse = logf(se) + mx;
#pragma unroll
        for (int j = 0; j < 10; ++j) out[(size_t)nid * OUT_C + j] = z[j] - lse;
    }
}

extern "C" void kernel_launch(void* const* d_in, const int* in_sizes, int n_in,
                              void* d_out, int out_size, void* d_ws, size_t ws_size,
                              hipStream_t stream) {
    const float* x   = (const float*)d_in[0];
    const int*   ei  = (const int*)d_in[1];
    const float* W1l = (const float*)d_in[2];
    const float* W1r = (const float*)d_in[3];
    const float* b1  = (const float*)d_in[4];
    const float* W2l = (const float*)d_in[5];
    const float* W2r = (const float*)d_in[6];
    const float* b2  = (const float*)d_in[7];
    float* out = (float*)d_out;
    const int* src = ei;
    const int* dst = ei + N_EDGES;

    char* w = (char*)d_ws;
    size_t off = 0;
    auto alloc = [&](size_t bytes) -> void* {
        void* p = w + off;
        off = (off + bytes + 255) & ~(size_t)255;
        return p;
    };
    __hip_bfloat16* Wt   = (__hip_bfloat16*)alloc((size_t)2 * HID_C * IN_C * 2);
    float*          Wt2f = (float*)alloc((size_t)32 * 256 * 4);
    __hip_bfloat16* Ab   = (__hip_bfloat16*)alloc((size_t)N_NODES * HID_C * 2);
    __hip_bfloat16* Bh   = (__hip_bfloat16*)alloc((size_t)N_NODES * HID_C * 2);
    float* CDl = (float*)alloc((size_t)N_NODES * 12 * 4);
    float* CDr = (float*)alloc((size_t)N_NODES * 12 * 4);
    int* cnt      = (int*)alloc((size_t)N_NODES * 4);
    unsigned short* slots = (unsigned short*)alloc((size_t)N_NODES * SLOT_CAP * 2);
    int* g_cursor = (int*)alloc((size_t)NBUCKET * 4);
    int* ebuf     = (int*)alloc((size_t)NBUCKET * EBUF_CAP * 4);

    (void)hipMemsetAsync(g_cursor, 0, (size_t)NBUCKET * 4, stream);

    k_pp<<<PREP_BLOCKS + PART_BLOCKS, 256, 0, stream>>>(W1l, W1r, W2l, W2r, Wt, Wt2f,
                                                        src, dst, g_cursor, ebuf);
    k_gb<<<NBUCKET + 8 * 196, 256, 0, stream>>>(ebuf, g_cursor, cnt, slots,
                                                x, Wt, b1, Ab, Bh);
    k_agg1f<<<N_NODES / 4, 256, 0, stream>>>(Ab, Bh, cnt, slots, Wt2f, b2, CDl, CDr);
    k_agg2<<<N_NODES / 8, 256, 0, stream>>>(CDl, CDr, cnt, slots, out);
}